// Round 1
// baseline (9616.973 us; speedup 1.0000x reference)
//
#include <hip/hip_runtime.h>
#include <math.h>

#define NB 8192
#define NK 4096
#define ND 1024
#define NL 8
#define RES_THR 1e-3f
#define KSPLIT 4

__device__ __forceinline__ float wave_reduce_sum(float v) {
#pragma unroll
  for (int off = 32; off > 0; off >>= 1) v += __shfl_down(v, off);
  return v;
}

// Copy targets -> residual (in d_out), compute initial active flags.
__global__ __launch_bounds__(256) void k_init(const float* __restrict__ tgt,
                                              float* __restrict__ resid,
                                              int* __restrict__ active) {
  int b = blockIdx.x;
  int t = threadIdx.x;
  float4 v = ((const float4*)(tgt + (size_t)b * ND))[t];
  ((float4*)(resid + (size_t)b * ND))[t] = v;
  float ss = v.x * v.x + v.y * v.y + v.z * v.z + v.w * v.w;
  ss = wave_reduce_sum(ss);
  __shared__ float red[4];
  if ((t & 63) == 0) red[t >> 6] = ss;
  __syncthreads();
  if (t == 0) {
    float tot = red[0] + red[1] + red[2] + red[3];
    active[b] = (sqrtf(tot) >= RES_THR) ? 1 : 0;
  }
}

// Fused scores + argmax. Each block: 64 rows x 1024 codebook cols (1/4 K-split).
// LDS tiles As/Bs are 64x64 f32, XOR-swizzled at 16B granularity.
__global__ __launch_bounds__(256) void k_score(const float* __restrict__ resid,
                                               const float* __restrict__ cb,
                                               float* __restrict__ bestv,
                                               int* __restrict__ besti) {
  __shared__ float As[64 * 64];
  __shared__ float Bs[64 * 64];
  const int blk = blockIdx.x;
  const int m0 = (blk >> 2) << 6;    // row tile base
  const int ks = blk & 3;            // K-split slice
  const int nbeg = ks << 10;         // 1024 cols per slice
  const int tid = threadIdx.x;
  const int tm = tid >> 4;   // 0..15
  const int tn = tid & 15;   // 0..15
  const int xa = tm & 7;
  const int xb = tn & 7;

  float bv[4];
  int bk[4];
#pragma unroll
  for (int i = 0; i < 4; ++i) { bv[i] = -INFINITY; bk[i] = 0; }

  for (int n0 = nbeg; n0 < nbeg + (NK / KSPLIT); n0 += 64) {
    float acc[4][4];
#pragma unroll
    for (int i = 0; i < 4; ++i)
#pragma unroll
      for (int j = 0; j < 4; ++j) acc[i][j] = 0.f;

    for (int d0 = 0; d0 < ND; d0 += 64) {
      __syncthreads();
#pragma unroll
      for (int it = 0; it < 4; ++it) {
        int q = it * 256 + tid;
        int r = q >> 4;       // 0..63 tile row
        int db = q & 15;      // 16B block within row
        float4 av = *(const float4*)(resid + (size_t)(m0 + r) * ND + d0 + db * 4);
        float4 bw = *(const float4*)(cb + (size_t)(n0 + r) * ND + d0 + db * 4);
        *(float4*)(&As[r * 64 + ((db ^ (r & 7)) << 2)]) = av;
        *(float4*)(&Bs[r * 64 + ((db ^ (r & 7)) << 2)]) = bw;
      }
      __syncthreads();
#pragma unroll
      for (int dq = 0; dq < 16; ++dq) {
        float4 a[4], b[4];
#pragma unroll
        for (int i = 0; i < 4; ++i) {
          a[i] = *(const float4*)(&As[(tm + 16 * i) * 64 + ((dq ^ xa) << 2)]);
          b[i] = *(const float4*)(&Bs[(tn + 16 * i) * 64 + ((dq ^ xb) << 2)]);
        }
#pragma unroll
        for (int i = 0; i < 4; ++i)
#pragma unroll
          for (int j = 0; j < 4; ++j) {
            acc[i][j] += a[i].x * b[j].x;
            acc[i][j] += a[i].y * b[j].y;
            acc[i][j] += a[i].z * b[j].z;
            acc[i][j] += a[i].w * b[j].w;
          }
      }
    }
    // fused argmax over this 64-col tile
#pragma unroll
    for (int i = 0; i < 4; ++i) {
      float v = acc[i][0];
      int k = n0 + tn;
#pragma unroll
      for (int j = 1; j < 4; ++j) {
        if (acc[i][j] > v) { v = acc[i][j]; k = n0 + tn + 16 * j; }
      }
#pragma unroll
      for (int msk = 1; msk < 16; msk <<= 1) {
        float ov = __shfl_xor(v, msk);
        int ok = __shfl_xor(k, msk);
        if (ov > v || (ov == v && ok < k)) { v = ov; k = ok; }
      }
      if (v > bv[i] || (v == bv[i] && k < bk[i])) { bv[i] = v; bk[i] = k; }
    }
  }
  if (tn == 0) {
#pragma unroll
    for (int i = 0; i < 4; ++i) {
      int m = m0 + tm + 16 * i;
      bestv[m * 4 + ks] = bv[i];
      besti[m * 4 + ks] = bk[i];
    }
  }
}

// Merge K-split candidates, update residual, emit index (as f32), update active.
__global__ __launch_bounds__(256) void k_update(float* __restrict__ resid,
                                                const float* __restrict__ cb,
                                                const float* __restrict__ bestv,
                                                const int* __restrict__ besti,
                                                int* __restrict__ active,
                                                float* __restrict__ out_idx,
                                                float decay, int s) {
  int b = blockIdx.x;
  int t = threadIdx.x;
  float v = bestv[b * 4];
  int k = besti[b * 4];
#pragma unroll
  for (int j = 1; j < 4; ++j) {
    float v2 = bestv[b * 4 + j];
    int k2 = besti[b * 4 + j];
    if (v2 > v || (v2 == v && k2 < k)) { v = v2; k = k2; }
  }
  int act = active[b];
  float4 r = ((float4*)(resid + (size_t)b * ND))[t];
  float4 c = ((const float4*)(cb + (size_t)k * ND))[t];
  if (act) {
    r.x -= decay * c.x;
    r.y -= decay * c.y;
    r.z -= decay * c.z;
    r.w -= decay * c.w;
  }
  ((float4*)(resid + (size_t)b * ND))[t] = r;
  float ss = r.x * r.x + r.y * r.y + r.z * r.z + r.w * r.w;
  ss = wave_reduce_sum(ss);
  __shared__ float red[4];
  if ((t & 63) == 0) red[t >> 6] = ss;
  __syncthreads();
  if (t == 0) {
    float tot = red[0] + red[1] + red[2] + red[3];
    out_idx[b * NL + s] = act ? (float)k : -1.0f;
    active[b] = (act && (sqrtf(tot) >= RES_THR)) ? 1 : 0;
  }
}

extern "C" void kernel_launch(void* const* d_in, const int* in_sizes, int n_in,
                              void* d_out, int out_size, void* d_ws, size_t ws_size,
                              hipStream_t stream) {
  const float* targets = (const float*)d_in[0];
  const float* codebook = (const float*)d_in[1];
  float* out = (float*)d_out;
  float* out_idx = out;                 // [8192][8] indices stored as f32
  float* resid = out + (size_t)NB * NL; // [8192][1024] residual (working + final)

  char* ws = (char*)d_ws;
  int* active = (int*)ws;                                   // 8192 ints
  float* bestv = (float*)(ws + (size_t)NB * 4);             // 8192*4 f32
  int* besti = (int*)(ws + (size_t)NB * 4 + (size_t)NB * 16);  // 8192*4 int

  k_init<<<NB, 256, 0, stream>>>(targets, resid, active);
  for (int s = 0; s < NL; ++s) {
    k_score<<<(NB / 64) * KSPLIT, 256, 0, stream>>>(resid, codebook, bestv, besti);
    float decay = powf(0.9f, (float)s);
    k_update<<<NB, 256, 0, stream>>>(resid, codebook, bestv, besti, active,
                                     out_idx, decay, s);
  }
}

// Round 4
// 3696.830 us; speedup vs baseline: 2.6014x; 2.6014x over previous
//
#include <hip/hip_runtime.h>
#include <hip/hip_bf16.h>
#include <math.h>

#define NB 8192
#define NK 4096
#define ND 1024
#define NL 8
#define KK 2048            // stored row length: [hi(1024) | lo(1024)]
#define RES_THR 1e-3f
#define MARGIN 0.05f

typedef __bf16 bf16x8 __attribute__((ext_vector_type(8)));
typedef float f32x4 __attribute__((ext_vector_type(4)));

#define MFMA16(a, b, c) __builtin_amdgcn_mfma_f32_16x16x32_bf16(a, b, c, 0, 0, 0)

#define GLOAD(g, l)                                                        \
  __builtin_amdgcn_global_load_lds(                                        \
      (const __attribute__((address_space(1))) void*)(g),                  \
      (__attribute__((address_space(3))) void*)(l), 16, 0, 0)

__device__ __forceinline__ unsigned short f2bf(float x) {
  __hip_bfloat16 h = __float2bfloat16(x);
  return __builtin_bit_cast(unsigned short, h);
}
__device__ __forceinline__ float bf2f(unsigned short u) {
  return __bfloat162float(__builtin_bit_cast(__hip_bfloat16, u));
}

__device__ __forceinline__ float wave_reduce_sum(float v) {
#pragma unroll
  for (int off = 32; off > 0; off >>= 1) v += __shfl_down(v, off);
  return v;
}

__device__ __forceinline__ void top2_merge(float& v1, int& k1, float& v2,
                                           int& k2, float w1, int j1, float w2,
                                           int j2) {
  if (w1 > v1 || (w1 == v1 && j1 < k1)) {
    if (v1 > w2 || (v1 == w2 && k1 < j2)) { v2 = v1; k2 = k1; }
    else { v2 = w2; k2 = j2; }
    v1 = w1; k1 = j1;
  } else {
    if (w1 > v2 || (w1 == v2 && j1 < k2)) { v2 = w1; k2 = j1; }
  }
}

// Prep codebook hi/lo bf16: B2[NK][KK]
__global__ __launch_bounds__(256) void k_prep(const float* __restrict__ cb,
                                              unsigned short* __restrict__ B2) {
  int b = blockIdx.x, t = threadIdx.x;
  float4 v = ((const float4*)(cb + (size_t)b * ND))[t];
  ushort4 h, l;
  h.x = f2bf(v.x); l.x = f2bf(v.x - bf2f(h.x));
  h.y = f2bf(v.y); l.y = f2bf(v.y - bf2f(h.y));
  h.z = f2bf(v.z); l.z = f2bf(v.z - bf2f(h.z));
  h.w = f2bf(v.w); l.w = f2bf(v.w - bf2f(h.w));
  ((ushort4*)(B2 + (size_t)b * KK))[t] = h;
  ((ushort4*)(B2 + (size_t)b * KK + ND))[t] = l;
}

// Init: A2 = hi/lo(targets) (A2 lives in d_out residual region), active flags.
__global__ __launch_bounds__(256) void k_init(const float* __restrict__ tgt,
                                              unsigned short* __restrict__ A2,
                                              int* __restrict__ active) {
  int b = blockIdx.x, t = threadIdx.x;
  float4 v = ((const float4*)(tgt + (size_t)b * ND))[t];
  ushort4 h, l;
  h.x = f2bf(v.x); l.x = f2bf(v.x - bf2f(h.x));
  h.y = f2bf(v.y); l.y = f2bf(v.y - bf2f(h.y));
  h.z = f2bf(v.z); l.z = f2bf(v.z - bf2f(h.z));
  h.w = f2bf(v.w); l.w = f2bf(v.w - bf2f(h.w));
  ((ushort4*)(A2 + (size_t)b * KK))[t] = h;
  ((ushort4*)(A2 + (size_t)b * KK + ND))[t] = l;
  float ss = v.x * v.x + v.y * v.y + v.z * v.z + v.w * v.w;
  ss = wave_reduce_sum(ss);
  __shared__ float red[4];
  if ((t & 63) == 0) red[t >> 6] = ss;
  __syncthreads();
  if (t == 0) {
    float tot = red[0] + red[1] + red[2] + red[3];
    active[b] = (sqrtf(tot) >= RES_THR) ? 1 : 0;
  }
}

// Approx scores = ah*bh + al*bh + ah*bl (3 phases x 16 k-tiles of 64 = 48),
// fused per-row top-2 over each 128-col block. 128x128 tile, 4 waves.
__global__ __launch_bounds__(256) void k_score(
    const unsigned short* __restrict__ A2, const unsigned short* __restrict__ B2,
    float4* __restrict__ part) {
  __shared__ __align__(16) char sA[16384];
  __shared__ __align__(16) char sB[16384];
  const int tid = threadIdx.x;
  const int lane = tid & 63;
  const int wid = tid >> 6;
  const int bid = blockIdx.x;
  const int bm = (bid >> 5) << 7;
  const int bn = (bid & 31) << 7;
  const int wr = wid >> 1;
  const int wc = wid & 1;

  // staging: pre-swizzled global source, linear LDS dest (rule #21)
  const int srow = tid >> 3;
  const int sblk = (tid & 7) ^ (srow & 7);
  const unsigned short* aSrc = A2 + (size_t)(bm + srow) * KK + sblk * 8;
  const unsigned short* bSrc = B2 + (size_t)(bn + srow) * KK + sblk * 8;

  const int lr = lane & 15;
  const int lk = lane >> 4;
  const int swz = lr & 7;
  const int aRow = (wr * 64 + lr) * 128;
  const int bRow = (wc * 64 + lr) * 128;
  const int kb0 = ((lk ^ swz) << 4);
  const int kb1 = (((4 + lk) ^ swz) << 4);

  f32x4 acc[4][4];
#pragma unroll
  for (int m = 0; m < 4; ++m)
#pragma unroll
    for (int n = 0; n < 4; ++n) acc[m][n] = (f32x4)(0.f);

  for (int kt = 0; kt < 48; ++kt) {
    const int j = (kt & 15) << 6;     // k-tile offset within 1024-dim half
    const int ph = kt >> 4;           // 0: hh, 1: lh, 2: hl
    const int ka = j + (ph == 1 ? 1024 : 0);
    const int kb = j + (ph == 2 ? 1024 : 0);
#pragma unroll
    for (int q = 0; q < 4; ++q) {
      GLOAD(aSrc + (size_t)(q * 32) * KK + ka, sA + q * 4096 + wid * 1024);
      GLOAD(bSrc + (size_t)(q * 32) * KK + kb, sB + q * 4096 + wid * 1024);
    }
    __syncthreads();
    bf16x8 af[4], bf_[4];
#pragma unroll
    for (int m = 0; m < 4; ++m) af[m] = *(const bf16x8*)(sA + aRow + m * 2048 + kb0);
#pragma unroll
    for (int n = 0; n < 4; ++n) bf_[n] = *(const bf16x8*)(sB + bRow + n * 2048 + kb0);
#pragma unroll
    for (int m = 0; m < 4; ++m)
#pragma unroll
      for (int n = 0; n < 4; ++n) acc[m][n] = MFMA16(af[m], bf_[n], acc[m][n]);
#pragma unroll
    for (int m = 0; m < 4; ++m) af[m] = *(const bf16x8*)(sA + aRow + m * 2048 + kb1);
#pragma unroll
    for (int n = 0; n < 4; ++n) bf_[n] = *(const bf16x8*)(sB + bRow + n * 2048 + kb1);
#pragma unroll
    for (int m = 0; m < 4; ++m)
#pragma unroll
      for (int n = 0; n < 4; ++n) acc[m][n] = MFMA16(af[m], bf_[n], acc[m][n]);
    __syncthreads();
  }

  // fused top-2 per row over this block's 128 columns
  float* red = (float*)sA;
#pragma unroll
  for (int m = 0; m < 4; ++m) {
#pragma unroll
    for (int q = 0; q < 4; ++q) {
      float v1 = acc[m][0][q];
      int k1 = bn + wc * 64 + lr;
      float v2 = -INFINITY;
      int k2 = 0x7fffffff;
#pragma unroll
      for (int n = 1; n < 4; ++n) {
        top2_merge(v1, k1, v2, k2, acc[m][n][q], bn + wc * 64 + n * 16 + lr,
                   -INFINITY, 0x7fffffff);
      }
#pragma unroll
      for (int msk = 1; msk < 16; msk <<= 1) {
        float ov1 = __shfl_xor(v1, msk);
        int ok1 = __shfl_xor(k1, msk);
        float ov2 = __shfl_xor(v2, msk);
        int ok2 = __shfl_xor(k2, msk);
        top2_merge(v1, k1, v2, k2, ov1, ok1, ov2, ok2);
      }
      if (lr == 0) {
        int row = wr * 64 + m * 16 + lk * 4 + q;
        ((float4*)red)[row * 2 + wc] =
            make_float4(v1, __int_as_float(k1), v2, __int_as_float(k2));
      }
    }
  }
  __syncthreads();
  if (tid < 128) {
    float4 e0 = ((float4*)red)[tid * 2 + 0];
    float4 e1 = ((float4*)red)[tid * 2 + 1];
    float v1 = e0.x; int k1 = __float_as_int(e0.y);
    float v2 = e0.z; int k2 = __float_as_int(e0.w);
    top2_merge(v1, k1, v2, k2, e1.x, __float_as_int(e1.y), e1.z,
               __float_as_int(e1.w));
    part[(size_t)(bm + tid) * 32 + (bid & 31)] =
        make_float4(v1, __int_as_float(k1), v2, __int_as_float(k2));
  }
}

// Merge partials, exact fp32 rescore of margin candidates on r=hi+lo,
// update residual (stored as hi/lo in rbuf; f32 on last step).
__global__ __launch_bounds__(256) void k_update(
    void* rbuf, const float* __restrict__ cb, const float4* __restrict__ part,
    int* __restrict__ active, float* __restrict__ out_idx, float decay, int s,
    int last) {
  int b = blockIdx.x, t = threadIdx.x;
  __shared__ int s_cnt;
  __shared__ int s_k[16];
  __shared__ float s_red[4];
  __shared__ float s_bv;
  __shared__ int s_bk;

  unsigned short* A2 = (unsigned short*)rbuf;
  const ushort4* a2r = (const ushort4*)(A2 + (size_t)b * KK);
  ushort4 hh = a2r[t];
  ushort4 ll = a2r[256 + t];
  float4 r;
  r.x = bf2f(hh.x) + bf2f(ll.x);
  r.y = bf2f(hh.y) + bf2f(ll.y);
  r.z = bf2f(hh.z) + bf2f(ll.z);
  r.w = bf2f(hh.w) + bf2f(ll.w);

  if (t < 64) {
    float4 e = part[(size_t)b * 32 + (t >> 1)];
    float v = (t & 1) ? e.z : e.x;
    int k = __float_as_int((t & 1) ? e.w : e.y);
    float M = v;
#pragma unroll
    for (int off = 32; off > 0; off >>= 1) M = fmaxf(M, __shfl_xor(M, off));
    bool cand = (v >= M - MARGIN);
    unsigned long long mask = __ballot(cand);
    int slot = __popcll(mask & ((1ull << t) - 1ull));
    if (cand && slot < 16) s_k[slot] = k;
    if (t == 0) {
      int n = (int)__popcll(mask);
      s_cnt = n < 16 ? n : 16;
      s_bv = -INFINITY;
      s_bk = 0x7fffffff;
    }
  }
  __syncthreads();
  int cnt = s_cnt;
  for (int c = 0; c < cnt; ++c) {
    int k = s_k[c];
    float4 cv = ((const float4*)(cb + (size_t)k * ND))[t];
    float d = r.x * cv.x + r.y * cv.y + r.z * cv.z + r.w * cv.w;
    d = wave_reduce_sum(d);
    if ((t & 63) == 0) s_red[t >> 6] = d;
    __syncthreads();
    if (t == 0) {
      float sc = s_red[0] + s_red[1] + s_red[2] + s_red[3];
      if (sc > s_bv || (sc == s_bv && k < s_bk)) { s_bv = sc; s_bk = k; }
    }
    __syncthreads();
  }
  int kbest = s_bk;
  int act = active[b];
  float4 cv = ((const float4*)(cb + (size_t)kbest * ND))[t];
  if (act) {
    r.x -= decay * cv.x;
    r.y -= decay * cv.y;
    r.z -= decay * cv.z;
    r.w -= decay * cv.w;
  }
  if (last) {
    ((float4*)((float*)rbuf + (size_t)b * ND))[t] = r;
  } else {
    ushort4 h, l;
    h.x = f2bf(r.x); l.x = f2bf(r.x - bf2f(h.x));
    h.y = f2bf(r.y); l.y = f2bf(r.y - bf2f(h.y));
    h.z = f2bf(r.z); l.z = f2bf(r.z - bf2f(h.z));
    h.w = f2bf(r.w); l.w = f2bf(r.w - bf2f(h.w));
    ((ushort4*)(A2 + (size_t)b * KK))[t] = h;
    ((ushort4*)(A2 + (size_t)b * KK + ND))[t] = l;
  }
  float ss = r.x * r.x + r.y * r.y + r.z * r.z + r.w * r.w;
  ss = wave_reduce_sum(ss);
  if ((t & 63) == 0) s_red[t >> 6] = ss;
  __syncthreads();
  if (t == 0) {
    float tot = s_red[0] + s_red[1] + s_red[2] + s_red[3];
    out_idx[(size_t)b * NL + s] = act ? (float)kbest : -1.0f;
    active[b] = (act && sqrtf(tot) >= RES_THR) ? 1 : 0;
  }
}

extern "C" void kernel_launch(void* const* d_in, const int* in_sizes, int n_in,
                              void* d_out, int out_size, void* d_ws,
                              size_t ws_size, hipStream_t stream) {
  const float* targets = (const float*)d_in[0];
  const float* codebook = (const float*)d_in[1];
  float* out = (float*)d_out;
  float* out_idx = out;                          // [8192][8] indices as f32
  void* rbuf = (void*)(out + (size_t)NB * NL);   // 32MB: A2 hi/lo during loop,
                                                 // f32 residual at the end
  char* ws = (char*)d_ws;
  float4* part = (float4*)ws;                          // 4MB
  int* active = (int*)(ws + (size_t)4 * 1024 * 1024);  // 32KB
  unsigned short* B2 =
      (unsigned short*)(ws + (size_t)4 * 1024 * 1024 + 65536);  // 16MB

  unsigned short* A2 = (unsigned short*)rbuf;

  k_prep<<<NK, 256, 0, stream>>>(codebook, B2);
  k_init<<<NB, 256, 0, stream>>>(targets, A2, active);
  for (int s = 0; s < NL; ++s) {
    k_score<<<(NB / 128) * (NK / 128), 256, 0, stream>>>(A2, B2, part);
    float decay = (float)pow(0.9, (double)s);
    k_update<<<NB, 256, 0, stream>>>(rbuf, codebook, part, active, out_idx,
                                     decay, s, s == NL - 1 ? 1 : 0);
  }
}

// Round 5
// 2528.471 us; speedup vs baseline: 3.8035x; 1.4621x over previous
//
#include <hip/hip_runtime.h>
#include <hip/hip_bf16.h>
#include <math.h>

#define NB 8192
#define NK 4096
#define ND 1024
#define NL 8
#define RES_THR 1e-3f
#define MARGIN 2.5f

typedef __bf16 bf16x8 __attribute__((ext_vector_type(8)));
typedef float f32x4 __attribute__((ext_vector_type(4)));

#define MFMA16(a, b, c) __builtin_amdgcn_mfma_f32_16x16x32_bf16(a, b, c, 0, 0, 0)

#define GLOAD(g, l)                                                        \
  __builtin_amdgcn_global_load_lds(                                        \
      (const __attribute__((address_space(1))) void*)(g),                  \
      (__attribute__((address_space(3))) void*)(l), 16, 0, 0)

__device__ __forceinline__ unsigned short f2bf(float x) {
  __hip_bfloat16 h = __float2bfloat16(x);
  return __builtin_bit_cast(unsigned short, h);
}

__device__ __forceinline__ float wave_reduce_sum(float v) {
#pragma unroll
  for (int off = 32; off > 0; off >>= 1) v += __shfl_down(v, off);
  return v;
}

__device__ __forceinline__ void top2_merge(float& v1, int& k1, float& v2,
                                           int& k2, float w1, int j1, float w2,
                                           int j2) {
  if (w1 > v1 || (w1 == v1 && j1 < k1)) {
    if (v1 > w2 || (v1 == w2 && k1 < j2)) { v2 = v1; k2 = k1; }
    else { v2 = w2; k2 = j2; }
    v1 = w1; k1 = j1;
  } else {
    if (w1 > v2 || (w1 == v2 && j1 < k2)) { v2 = w1; k2 = j1; }
  }
}

// Prep codebook hi bf16: Bh[NK][ND]
__global__ __launch_bounds__(256) void k_prep(const float* __restrict__ cb,
                                              unsigned short* __restrict__ Bh) {
  int b = blockIdx.x, t = threadIdx.x;
  float4 v = ((const float4*)(cb + (size_t)b * ND))[t];
  ushort4 h;
  h.x = f2bf(v.x); h.y = f2bf(v.y); h.z = f2bf(v.z); h.w = f2bf(v.w);
  ((ushort4*)(Bh + (size_t)b * ND))[t] = h;
}

// Init: residual(f32, in d_out) = targets; Ah = bf16(targets); active flags.
__global__ __launch_bounds__(256) void k_init(const float* __restrict__ tgt,
                                              float* __restrict__ resid,
                                              unsigned short* __restrict__ Ah,
                                              int* __restrict__ active) {
  int b = blockIdx.x, t = threadIdx.x;
  float4 v = ((const float4*)(tgt + (size_t)b * ND))[t];
  ((float4*)(resid + (size_t)b * ND))[t] = v;
  ushort4 h;
  h.x = f2bf(v.x); h.y = f2bf(v.y); h.z = f2bf(v.z); h.w = f2bf(v.w);
  ((ushort4*)(Ah + (size_t)b * ND))[t] = h;
  float ss = v.x * v.x + v.y * v.y + v.z * v.z + v.w * v.w;
  ss = wave_reduce_sum(ss);
  __shared__ float red[4];
  if ((t & 63) == 0) red[t >> 6] = ss;
  __syncthreads();
  if (t == 0) {
    float tot = red[0] + red[1] + red[2] + red[3];
    active[b] = (sqrtf(tot) >= RES_THR) ? 1 : 0;
  }
}

// Approx scores = bf16(r) . bf16(c) over K=1024 (16 k-tiles of 64),
// fused per-row top-2 over each 128-col block. 128x128 tile, 4 waves.
__global__ __launch_bounds__(256) void k_score(
    const unsigned short* __restrict__ Ah, const unsigned short* __restrict__ Bh,
    float4* __restrict__ part) {
  __shared__ __align__(16) char sA[16384];
  __shared__ __align__(16) char sB[16384];
  const int tid = threadIdx.x;
  const int lane = tid & 63;
  const int wid = tid >> 6;
  const int bid = blockIdx.x;
  const int bm = (bid >> 5) << 7;
  const int bn = (bid & 31) << 7;
  const int wr = wid >> 1;
  const int wc = wid & 1;

  // staging: pre-swizzled global source, linear LDS dest (rule #21)
  const int srow = tid >> 3;
  const int sblk = (tid & 7) ^ (srow & 7);
  const unsigned short* aSrc = Ah + (size_t)(bm + srow) * ND + sblk * 8;
  const unsigned short* bSrc = Bh + (size_t)(bn + srow) * ND + sblk * 8;

  const int lr = lane & 15;
  const int lk = lane >> 4;
  const int swz = lr & 7;
  const int aRow = (wr * 64 + lr) * 128;
  const int bRow = (wc * 64 + lr) * 128;
  const int kb0 = ((lk ^ swz) << 4);
  const int kb1 = (((4 + lk) ^ swz) << 4);

  f32x4 acc[4][4];
#pragma unroll
  for (int m = 0; m < 4; ++m)
#pragma unroll
    for (int n = 0; n < 4; ++n) acc[m][n] = (f32x4)(0.f);

  for (int kt = 0; kt < 16; ++kt) {
    const int k0 = kt << 6;
#pragma unroll
    for (int q = 0; q < 4; ++q) {
      GLOAD(aSrc + (size_t)(q * 32) * ND + k0, sA + q * 4096 + wid * 1024);
      GLOAD(bSrc + (size_t)(q * 32) * ND + k0, sB + q * 4096 + wid * 1024);
    }
    __syncthreads();
    bf16x8 af[4], bf_[4];
#pragma unroll
    for (int m = 0; m < 4; ++m) af[m] = *(const bf16x8*)(sA + aRow + m * 2048 + kb0);
#pragma unroll
    for (int n = 0; n < 4; ++n) bf_[n] = *(const bf16x8*)(sB + bRow + n * 2048 + kb0);
#pragma unroll
    for (int m = 0; m < 4; ++m)
#pragma unroll
      for (int n = 0; n < 4; ++n) acc[m][n] = MFMA16(af[m], bf_[n], acc[m][n]);
#pragma unroll
    for (int m = 0; m < 4; ++m) af[m] = *(const bf16x8*)(sA + aRow + m * 2048 + kb1);
#pragma unroll
    for (int n = 0; n < 4; ++n) bf_[n] = *(const bf16x8*)(sB + bRow + n * 2048 + kb1);
#pragma unroll
    for (int m = 0; m < 4; ++m)
#pragma unroll
      for (int n = 0; n < 4; ++n) acc[m][n] = MFMA16(af[m], bf_[n], acc[m][n]);
    __syncthreads();
  }

  // fused top-2 per row over this block's 128 columns
  float* red = (float*)sA;
#pragma unroll
  for (int m = 0; m < 4; ++m) {
#pragma unroll
    for (int q = 0; q < 4; ++q) {
      float v1 = acc[m][0][q];
      int k1 = bn + wc * 64 + lr;
      float v2 = -INFINITY;
      int k2 = 0x7fffffff;
#pragma unroll
      for (int n = 1; n < 4; ++n) {
        top2_merge(v1, k1, v2, k2, acc[m][n][q], bn + wc * 64 + n * 16 + lr,
                   -INFINITY, 0x7fffffff);
      }
#pragma unroll
      for (int msk = 1; msk < 16; msk <<= 1) {
        float ov1 = __shfl_xor(v1, msk);
        int ok1 = __shfl_xor(k1, msk);
        float ov2 = __shfl_xor(v2, msk);
        int ok2 = __shfl_xor(k2, msk);
        top2_merge(v1, k1, v2, k2, ov1, ok1, ov2, ok2);
      }
      if (lr == 0) {
        int row = wr * 64 + m * 16 + lk * 4 + q;
        ((float4*)red)[row * 2 + wc] =
            make_float4(v1, __int_as_float(k1), v2, __int_as_float(k2));
      }
    }
  }
  __syncthreads();
  if (tid < 128) {
    float4 e0 = ((float4*)red)[tid * 2 + 0];
    float4 e1 = ((float4*)red)[tid * 2 + 1];
    float v1 = e0.x; int k1 = __float_as_int(e0.y);
    float v2 = e0.z; int k2 = __float_as_int(e0.w);
    top2_merge(v1, k1, v2, k2, e1.x, __float_as_int(e1.y), e1.z,
               __float_as_int(e1.w));
    part[(size_t)(bm + tid) * 32 + (bid & 31)] =
        make_float4(v1, __int_as_float(k1), v2, __int_as_float(k2));
  }
}

// Merge partials, exact fp32 rescore of margin candidates, update residual
// (f32, in d_out), refresh Ah, active, emit index.
__global__ __launch_bounds__(256) void k_update(
    float* __restrict__ resid, const float* __restrict__ cb,
    const float4* __restrict__ part, int* __restrict__ active,
    float* __restrict__ out_idx, unsigned short* __restrict__ Ah, float decay,
    int s) {
  int b = blockIdx.x, t = threadIdx.x;
  __shared__ int s_cnt;
  __shared__ int s_k[16];
  __shared__ float s_red[4];
  __shared__ float s_bv;
  __shared__ int s_bk;

  float4 r = ((const float4*)(resid + (size_t)b * ND))[t];

  if (t < 64) {
    float4 e = part[(size_t)b * 32 + (t >> 1)];
    float v = (t & 1) ? e.z : e.x;
    int k = __float_as_int((t & 1) ? e.w : e.y);
    float M = v;
#pragma unroll
    for (int off = 32; off > 0; off >>= 1) M = fmaxf(M, __shfl_xor(M, off));
    bool cand = (v >= M - MARGIN);
    unsigned long long mask = __ballot(cand);
    int slot = __popcll(mask & ((1ull << t) - 1ull));
    if (cand && slot < 16) s_k[slot] = k;
    if (t == 0) {
      int n = (int)__popcll(mask);
      s_cnt = n < 16 ? n : 16;
      s_bv = -INFINITY;
      s_bk = 0x7fffffff;
    }
  }
  __syncthreads();
  int cnt = s_cnt;
  for (int c = 0; c < cnt; ++c) {
    int k = s_k[c];
    float4 cv = ((const float4*)(cb + (size_t)k * ND))[t];
    float d = r.x * cv.x + r.y * cv.y + r.z * cv.z + r.w * cv.w;
    d = wave_reduce_sum(d);
    if ((t & 63) == 0) s_red[t >> 6] = d;
    __syncthreads();
    if (t == 0) {
      float sc = s_red[0] + s_red[1] + s_red[2] + s_red[3];
      if (sc > s_bv || (sc == s_bv && k < s_bk)) { s_bv = sc; s_bk = k; }
    }
    __syncthreads();
  }
  int kbest = s_bk;
  int act = active[b];
  float4 cv = ((const float4*)(cb + (size_t)kbest * ND))[t];
  if (act) {
    r.x -= decay * cv.x;
    r.y -= decay * cv.y;
    r.z -= decay * cv.z;
    r.w -= decay * cv.w;
  }
  ((float4*)(resid + (size_t)b * ND))[t] = r;
  ushort4 h;
  h.x = f2bf(r.x); h.y = f2bf(r.y); h.z = f2bf(r.z); h.w = f2bf(r.w);
  ((ushort4*)(Ah + (size_t)b * ND))[t] = h;
  float ss = r.x * r.x + r.y * r.y + r.z * r.z + r.w * r.w;
  ss = wave_reduce_sum(ss);
  if ((t & 63) == 0) s_red[t >> 6] = ss;
  __syncthreads();
  if (t == 0) {
    float tot = s_red[0] + s_red[1] + s_red[2] + s_red[3];
    out_idx[(size_t)b * NL + s] = act ? (float)kbest : -1.0f;
    active[b] = (act && sqrtf(tot) >= RES_THR) ? 1 : 0;
  }
}

extern "C" void kernel_launch(void* const* d_in, const int* in_sizes, int n_in,
                              void* d_out, int out_size, void* d_ws,
                              size_t ws_size, hipStream_t stream) {
  const float* targets = (const float*)d_in[0];
  const float* codebook = (const float*)d_in[1];
  float* out = (float*)d_out;
  float* out_idx = out;                   // [8192][8] indices as f32
  float* resid = out + (size_t)NB * NL;   // [8192][1024] f32 residual

  char* ws = (char*)d_ws;
  float4* part = (float4*)ws;                                    // 4MB
  int* active = (int*)(ws + (size_t)4 * 1024 * 1024);            // 64KB pad
  unsigned short* Ah =
      (unsigned short*)(ws + (size_t)4 * 1024 * 1024 + 65536);   // 16MB
  unsigned short* Bh = Ah + (size_t)NB * ND;                     // 8MB

  k_prep<<<NK, 256, 0, stream>>>(codebook, Bh);
  k_init<<<NB, 256, 0, stream>>>(targets, resid, Ah, active);
  for (int s = 0; s < NL; ++s) {
    k_score<<<(NB / 128) * (NK / 128), 256, 0, stream>>>(Ah, Bh, part);
    float decay = (float)pow(0.9, (double)s);
    k_update<<<NB, 256, 0, stream>>>(resid, codebook, part, active, out_idx, Ah,
                                     decay, s);
  }
}

// Round 6
// 2432.438 us; speedup vs baseline: 3.9536x; 1.0395x over previous
//
#include <hip/hip_runtime.h>
#include <hip/hip_bf16.h>
#include <math.h>

#define NB 8192
#define NK 4096
#define ND 1024
#define NL 8
#define RES_THR 1e-3f
#define MARGIN 2.5f

typedef __bf16 bf16x8 __attribute__((ext_vector_type(8)));
typedef float f32x4 __attribute__((ext_vector_type(4)));

#define MFMA16(a, b, c) __builtin_amdgcn_mfma_f32_16x16x32_bf16(a, b, c, 0, 0, 0)

#define GLOAD(g, l)                                                        \
  __builtin_amdgcn_global_load_lds(                                        \
      (const __attribute__((address_space(1))) void*)(g),                  \
      (__attribute__((address_space(3))) void*)(l), 16, 0, 0)

__device__ __forceinline__ unsigned short f2bf(float x) {
  __hip_bfloat16 h = __float2bfloat16(x);
  return __builtin_bit_cast(unsigned short, h);
}

__device__ __forceinline__ float wave_reduce_sum(float v) {
#pragma unroll
  for (int off = 32; off > 0; off >>= 1) v += __shfl_down(v, off);
  return v;
}

__device__ __forceinline__ void top2_merge(float& v1, int& k1, float& v2,
                                           int& k2, float w1, int j1, float w2,
                                           int j2) {
  if (w1 > v1 || (w1 == v1 && j1 < k1)) {
    if (v1 > w2 || (v1 == w2 && k1 < j2)) { v2 = v1; k2 = k1; }
    else { v2 = w2; k2 = j2; }
    v1 = w1; k1 = j1;
  } else {
    if (w1 > v2 || (w1 == v2 && j1 < k2)) { v2 = w1; k2 = j1; }
  }
}

// Prep codebook hi bf16: Bh[NK][ND]
__global__ __launch_bounds__(256) void k_prep(const float* __restrict__ cb,
                                              unsigned short* __restrict__ Bh) {
  int b = blockIdx.x, t = threadIdx.x;
  float4 v = ((const float4*)(cb + (size_t)b * ND))[t];
  ushort4 h;
  h.x = f2bf(v.x); h.y = f2bf(v.y); h.z = f2bf(v.z); h.w = f2bf(v.w);
  ((ushort4*)(Bh + (size_t)b * ND))[t] = h;
}

// Init: residual(f32, in d_out) = targets; Ah = bf16(targets); active flags.
__global__ __launch_bounds__(256) void k_init(const float* __restrict__ tgt,
                                              float* __restrict__ resid,
                                              unsigned short* __restrict__ Ah,
                                              int* __restrict__ active) {
  int b = blockIdx.x, t = threadIdx.x;
  float4 v = ((const float4*)(tgt + (size_t)b * ND))[t];
  ((float4*)(resid + (size_t)b * ND))[t] = v;
  ushort4 h;
  h.x = f2bf(v.x); h.y = f2bf(v.y); h.z = f2bf(v.z); h.w = f2bf(v.w);
  ((ushort4*)(Ah + (size_t)b * ND))[t] = h;
  float ss = v.x * v.x + v.y * v.y + v.z * v.z + v.w * v.w;
  ss = wave_reduce_sum(ss);
  __shared__ float red[4];
  if ((t & 63) == 0) red[t >> 6] = ss;
  __syncthreads();
  if (t == 0) {
    float tot = red[0] + red[1] + red[2] + red[3];
    active[b] = (sqrtf(tot) >= RES_THR) ? 1 : 0;
  }
}

// Approx scores = bf16(r).bf16(c), K=1024. 256x256 tile, 8 waves (2Mx4N),
// BK=64, double-buffered LDS with prefetch-next-before-compute (2-phase).
// Fused per-row top-2 over this block's 256 columns -> part[row][16].
__global__ __launch_bounds__(512) void k_score(
    const unsigned short* __restrict__ Ah, const unsigned short* __restrict__ Bh,
    float4* __restrict__ part) {
  __shared__ __align__(16) char sA[2][32768];  // 256 rows x 64 bf16, swizzled
  __shared__ __align__(16) char sB[2][32768];
  const int tid = threadIdx.x;
  const int lane = tid & 63;
  const int bid = blockIdx.x;
  const int bm = bid >> 4;    // 0..31 row tile
  const int bn = bid & 15;    // 0..15 col tile
  const int wid = tid >> 6;   // 0..7
  const int wr = wid >> 2;    // 0..1 -> 128 rows
  const int wc = wid & 3;     // 0..3 -> 64 cols

  // staging source (pre-swizzled 16B block within row, rule #21)
  const int srow = tid >> 3;                 // 0..63
  const int sblk = (tid & 7) ^ (srow & 7);
  const unsigned short* aSrc = Ah + (size_t)(bm * 256 + srow) * ND + sblk * 8;
  const unsigned short* bSrc = Bh + (size_t)(bn * 256 + srow) * ND + sblk * 8;

  // fragment addressing
  const int lr = lane & 15;
  const int lk = lane >> 4;
  const int swz = lr & 7;
  const int kb0 = ((lk ^ swz) << 4);
  const int kb1 = (((4 + lk) ^ swz) << 4);

  f32x4 acc[8][4];
#pragma unroll
  for (int m = 0; m < 8; ++m)
#pragma unroll
    for (int n = 0; n < 4; ++n) acc[m][n] = (f32x4)(0.f);

  // prologue: stage k-tile 0 into buf 0
#pragma unroll
  for (int rr = 0; rr < 4; ++rr) {
    GLOAD(aSrc + (size_t)(rr * 64) * ND, &sA[0][rr * 8192 + tid * 16]);
    GLOAD(bSrc + (size_t)(rr * 64) * ND, &sB[0][rr * 8192 + tid * 16]);
  }
  __syncthreads();

  int cur = 0;
  for (int kt = 0; kt < 16; ++kt) {
    if (kt < 15) {
      const int k0 = (kt + 1) << 6;
#pragma unroll
      for (int rr = 0; rr < 4; ++rr) {
        GLOAD(aSrc + (size_t)(rr * 64) * ND + k0,
              &sA[cur ^ 1][rr * 8192 + tid * 16]);
        GLOAD(bSrc + (size_t)(rr * 64) * ND + k0,
              &sB[cur ^ 1][rr * 8192 + tid * 16]);
      }
    }
    const char* pa = sA[cur];
    const char* pb = sB[cur];
    bf16x8 af[8], bf_[4];
    // k-half 0
#pragma unroll
    for (int m = 0; m < 8; ++m)
      af[m] = *(const bf16x8*)(pa + (wr * 128 + m * 16 + lr) * 128 + kb0);
#pragma unroll
    for (int n = 0; n < 4; ++n)
      bf_[n] = *(const bf16x8*)(pb + (wc * 64 + n * 16 + lr) * 128 + kb0);
#pragma unroll
    for (int m = 0; m < 8; ++m)
#pragma unroll
      for (int n = 0; n < 4; ++n) acc[m][n] = MFMA16(af[m], bf_[n], acc[m][n]);
    // k-half 1
#pragma unroll
    for (int m = 0; m < 8; ++m)
      af[m] = *(const bf16x8*)(pa + (wr * 128 + m * 16 + lr) * 128 + kb1);
#pragma unroll
    for (int n = 0; n < 4; ++n)
      bf_[n] = *(const bf16x8*)(pb + (wc * 64 + n * 16 + lr) * 128 + kb1);
#pragma unroll
    for (int m = 0; m < 8; ++m)
#pragma unroll
      for (int n = 0; n < 4; ++n) acc[m][n] = MFMA16(af[m], bf_[n], acc[m][n]);
    __syncthreads();
    cur ^= 1;
  }

  // fused top-2 per row over this block's 256 columns
  float4* red = (float4*)sA;  // [256 rows][4 wave-cols]
#pragma unroll
  for (int m = 0; m < 8; ++m) {
#pragma unroll
    for (int q = 0; q < 4; ++q) {
      float v1 = acc[m][0][q];
      int k1 = bn * 256 + wc * 64 + lr;
      float v2 = -INFINITY;
      int k2 = 0x7fffffff;
#pragma unroll
      for (int n = 1; n < 4; ++n) {
        top2_merge(v1, k1, v2, k2, acc[m][n][q],
                   bn * 256 + wc * 64 + n * 16 + lr, -INFINITY, 0x7fffffff);
      }
#pragma unroll
      for (int msk = 1; msk < 16; msk <<= 1) {
        float ov1 = __shfl_xor(v1, msk);
        int ok1 = __shfl_xor(k1, msk);
        float ov2 = __shfl_xor(v2, msk);
        int ok2 = __shfl_xor(k2, msk);
        top2_merge(v1, k1, v2, k2, ov1, ok1, ov2, ok2);
      }
      if (lr == 0) {
        int row = wr * 128 + m * 16 + lk * 4 + q;
        red[row * 4 + wc] =
            make_float4(v1, __int_as_float(k1), v2, __int_as_float(k2));
      }
    }
  }
  __syncthreads();
  if (tid < 256) {
    float4 e0 = red[tid * 4 + 0];
    float v1 = e0.x; int k1 = __float_as_int(e0.y);
    float v2 = e0.z; int k2 = __float_as_int(e0.w);
#pragma unroll
    for (int j = 1; j < 4; ++j) {
      float4 e = red[tid * 4 + j];
      top2_merge(v1, k1, v2, k2, e.x, __float_as_int(e.y), e.z,
                 __float_as_int(e.w));
    }
    part[(size_t)(bm * 256 + tid) * 16 + bn] =
        make_float4(v1, __int_as_float(k1), v2, __int_as_float(k2));
  }
}

// Merge partials, exact fp32 rescore of margin candidates, update residual
// (f32, in d_out), refresh Ah, active, emit index.
__global__ __launch_bounds__(256) void k_update(
    float* __restrict__ resid, const float* __restrict__ cb,
    const float4* __restrict__ part, int* __restrict__ active,
    float* __restrict__ out_idx, unsigned short* __restrict__ Ah, float decay,
    int s) {
  int b = blockIdx.x, t = threadIdx.x;
  __shared__ int s_cnt;
  __shared__ int s_k[16];
  __shared__ float s_red[4];
  __shared__ float s_bv;
  __shared__ int s_bk;

  float4 r = ((const float4*)(resid + (size_t)b * ND))[t];

  if (t < 32) {
    float4 e = part[(size_t)b * 16 + (t >> 1)];
    float v = (t & 1) ? e.z : e.x;
    int k = __float_as_int((t & 1) ? e.w : e.y);
    float M = v;
#pragma unroll
    for (int off = 16; off > 0; off >>= 1) M = fmaxf(M, __shfl_xor(M, off));
    bool cand = (v >= M - MARGIN);
    unsigned long long mask = __ballot(cand);
    int slot = __popcll(mask & ((1ull << t) - 1ull));
    if (cand && slot < 16) s_k[slot] = k;
    if (t == 0) {
      int n = (int)__popcll(mask);
      s_cnt = n < 16 ? n : 16;
      s_bv = -INFINITY;
      s_bk = 0x7fffffff;
    }
  }
  __syncthreads();
  int cnt = s_cnt;
  for (int c = 0; c < cnt; ++c) {
    int k = s_k[c];
    float4 cv = ((const float4*)(cb + (size_t)k * ND))[t];
    float d = r.x * cv.x + r.y * cv.y + r.z * cv.z + r.w * cv.w;
    d = wave_reduce_sum(d);
    if ((t & 63) == 0) s_red[t >> 6] = d;
    __syncthreads();
    if (t == 0) {
      float sc = s_red[0] + s_red[1] + s_red[2] + s_red[3];
      if (sc > s_bv || (sc == s_bv && k < s_bk)) { s_bv = sc; s_bk = k; }
    }
    __syncthreads();
  }
  int kbest = s_bk;
  int act = active[b];
  float4 cv = ((const float4*)(cb + (size_t)kbest * ND))[t];
  if (act) {
    r.x -= decay * cv.x;
    r.y -= decay * cv.y;
    r.z -= decay * cv.z;
    r.w -= decay * cv.w;
  }
  ((float4*)(resid + (size_t)b * ND))[t] = r;
  ushort4 h;
  h.x = f2bf(r.x); h.y = f2bf(r.y); h.z = f2bf(r.z); h.w = f2bf(r.w);
  ((ushort4*)(Ah + (size_t)b * ND))[t] = h;
  float ss = r.x * r.x + r.y * r.y + r.z * r.z + r.w * r.w;
  ss = wave_reduce_sum(ss);
  if ((t & 63) == 0) s_red[t >> 6] = ss;
  __syncthreads();
  if (t == 0) {
    float tot = s_red[0] + s_red[1] + s_red[2] + s_red[3];
    out_idx[(size_t)b * NL + s] = act ? (float)kbest : -1.0f;
    active[b] = (act && sqrtf(tot) >= RES_THR) ? 1 : 0;
  }
}

extern "C" void kernel_launch(void* const* d_in, const int* in_sizes, int n_in,
                              void* d_out, int out_size, void* d_ws,
                              size_t ws_size, hipStream_t stream) {
  const float* targets = (const float*)d_in[0];
  const float* codebook = (const float*)d_in[1];
  float* out = (float*)d_out;
  float* out_idx = out;                   // [8192][8] indices as f32
  float* resid = out + (size_t)NB * NL;   // [8192][1024] f32 residual

  char* ws = (char*)d_ws;
  float4* part = (float4*)ws;                                    // 2MB
  int* active = (int*)(ws + (size_t)4 * 1024 * 1024);            // 64KB pad
  unsigned short* Ah =
      (unsigned short*)(ws + (size_t)4 * 1024 * 1024 + 65536);   // 16MB
  unsigned short* Bh = Ah + (size_t)NB * ND;                     // 8MB

  k_prep<<<NK, 256, 0, stream>>>(codebook, Bh);
  k_init<<<NB, 256, 0, stream>>>(targets, resid, Ah, active);
  for (int s = 0; s < NL; ++s) {
    k_score<<<(NB / 256) * (NK / 256), 512, 0, stream>>>(Ah, Bh, part);
    float decay = (float)pow(0.9, (double)s);
    k_update<<<NB, 256, 0, stream>>>(resid, codebook, part, active, out_idx, Ah,
                                     decay, s);
  }
}

// Round 7
// 2375.386 us; speedup vs baseline: 4.0486x; 1.0240x over previous
//
#include <hip/hip_runtime.h>
#include <hip/hip_bf16.h>
#include <math.h>

#define NB 8192
#define NK 4096
#define ND 1024
#define NL 8
#define RES_THR 1e-3f
#define MARGIN 2.5f

typedef __bf16 bf16x8 __attribute__((ext_vector_type(8)));
typedef float f32x4 __attribute__((ext_vector_type(4)));

#define MFMA16(a, b, c) __builtin_amdgcn_mfma_f32_16x16x32_bf16(a, b, c, 0, 0, 0)

#define GLOAD(g, l)                                                        \
  __builtin_amdgcn_global_load_lds(                                        \
      (const __attribute__((address_space(1))) void*)(g),                  \
      (__attribute__((address_space(3))) void*)(l), 16, 0, 0)

__device__ __forceinline__ unsigned short f2bf(float x) {
  __hip_bfloat16 h = __float2bfloat16(x);
  return __builtin_bit_cast(unsigned short, h);
}

__device__ __forceinline__ float wave_reduce_sum(float v) {
#pragma unroll
  for (int off = 32; off > 0; off >>= 1) v += __shfl_down(v, off);
  return v;
}

__device__ __forceinline__ void top2_merge(float& v1, int& k1, float& v2,
                                           int& k2, float w1, int j1, float w2,
                                           int j2) {
  if (w1 > v1 || (w1 == v1 && j1 < k1)) {
    if (v1 > w2 || (v1 == w2 && k1 < j2)) { v2 = v1; k2 = k1; }
    else { v2 = w2; k2 = j2; }
    v1 = w1; k1 = j1;
  } else {
    if (w1 > v2 || (w1 == v2 && j1 < k2)) { v2 = w1; k2 = j1; }
  }
}

// Prep codebook hi bf16: Bh[NK][ND]
__global__ __launch_bounds__(256) void k_prep(const float* __restrict__ cb,
                                              unsigned short* __restrict__ Bh) {
  int b = blockIdx.x, t = threadIdx.x;
  float4 v = ((const float4*)(cb + (size_t)b * ND))[t];
  ushort4 h;
  h.x = f2bf(v.x); h.y = f2bf(v.y); h.z = f2bf(v.z); h.w = f2bf(v.w);
  ((ushort4*)(Bh + (size_t)b * ND))[t] = h;
}

// Init: residual(f32, in d_out) = targets; Ah = bf16(targets); active flags.
__global__ __launch_bounds__(256) void k_init(const float* __restrict__ tgt,
                                              float* __restrict__ resid,
                                              unsigned short* __restrict__ Ah,
                                              int* __restrict__ active) {
  int b = blockIdx.x, t = threadIdx.x;
  float4 v = ((const float4*)(tgt + (size_t)b * ND))[t];
  ((float4*)(resid + (size_t)b * ND))[t] = v;
  ushort4 h;
  h.x = f2bf(v.x); h.y = f2bf(v.y); h.z = f2bf(v.z); h.w = f2bf(v.w);
  ((ushort4*)(Ah + (size_t)b * ND))[t] = h;
  float ss = v.x * v.x + v.y * v.y + v.z * v.z + v.w * v.w;
  ss = wave_reduce_sum(ss);
  __shared__ float red[4];
  if ((t & 63) == 0) red[t >> 6] = ss;
  __syncthreads();
  if (t == 0) {
    float tot = red[0] + red[1] + red[2] + red[3];
    active[b] = (sqrtf(tot) >= RES_THR) ? 1 : 0;
  }
}

// Approx scores = bf16(r).bf16(c), K=1024. 256x256 tile, 8 waves (2Mx4N),
// BK=64, double-buffered LDS, counted-vmcnt pipeline (2 K-tiles in flight,
// raw s_barrier, never drain vmcnt to 0 inside the loop).
__global__ __launch_bounds__(512) void k_score(
    const unsigned short* __restrict__ Ah, const unsigned short* __restrict__ Bh,
    float4* __restrict__ part) {
  __shared__ __align__(16) char sA[2][32768];  // 256 rows x 64 bf16, swizzled
  __shared__ __align__(16) char sB[2][32768];
  const int tid = threadIdx.x;
  const int lane = tid & 63;
  const int bid = blockIdx.x;
  const int bm = bid >> 4;    // 0..31 row tile
  const int bn = bid & 15;    // 0..15 col tile
  const int wid = tid >> 6;   // 0..7
  const int wr = wid >> 2;    // 0..1 -> 128 rows
  const int wc = wid & 3;     // 0..3 -> 64 cols

  // staging source (pre-swizzled 16B block within row, rule #21)
  const int srow = tid >> 3;                 // 0..63
  const int sblk = (tid & 7) ^ (srow & 7);
  const unsigned short* aSrc = Ah + (size_t)(bm * 256 + srow) * ND + sblk * 8;
  const unsigned short* bSrc = Bh + (size_t)(bn * 256 + srow) * ND + sblk * 8;

  // fragment addressing
  const int lr = lane & 15;
  const int lk = lane >> 4;
  const int swz = lr & 7;
  const int kb0 = ((lk ^ swz) << 4);
  const int kb1 = (((4 + lk) ^ swz) << 4);

  f32x4 acc[8][4];
#pragma unroll
  for (int m = 0; m < 8; ++m)
#pragma unroll
    for (int n = 0; n < 4; ++n) acc[m][n] = (f32x4)(0.f);

  // prologue: stage k-tiles 0 and 1 (8 loads each; 16 in flight)
#pragma unroll
  for (int rr = 0; rr < 4; ++rr) {
    GLOAD(aSrc + (size_t)(rr * 64) * ND, &sA[0][rr * 8192 + tid * 16]);
    GLOAD(bSrc + (size_t)(rr * 64) * ND, &sB[0][rr * 8192 + tid * 16]);
  }
#pragma unroll
  for (int rr = 0; rr < 4; ++rr) {
    GLOAD(aSrc + (size_t)(rr * 64) * ND + 64, &sA[1][rr * 8192 + tid * 16]);
    GLOAD(bSrc + (size_t)(rr * 64) * ND + 64, &sB[1][rr * 8192 + tid * 16]);
  }

#pragma unroll 1
  for (int kt = 0; kt < 15; ++kt) {
    // oldest 8 loads (tile kt) landed; tile kt+1's 8 stay in flight
    asm volatile("s_waitcnt vmcnt(8)" ::: "memory");
    __builtin_amdgcn_s_barrier();
    const char* pa = sA[kt & 1];
    const char* pb = sB[kt & 1];
    bf16x8 af0[8], bf0[4];
#pragma unroll
    for (int m = 0; m < 8; ++m)
      af0[m] = *(const bf16x8*)(pa + (wr * 128 + m * 16 + lr) * 128 + kb0);
#pragma unroll
    for (int n = 0; n < 4; ++n)
      bf0[n] = *(const bf16x8*)(pb + (wc * 64 + n * 16 + lr) * 128 + kb0);
    __builtin_amdgcn_s_setprio(1);
#pragma unroll
    for (int m = 0; m < 8; ++m)
#pragma unroll
      for (int n = 0; n < 4; ++n) acc[m][n] = MFMA16(af0[m], bf0[n], acc[m][n]);
    __builtin_amdgcn_s_setprio(0);
    __builtin_amdgcn_sched_barrier(0);
    bf16x8 af1[8], bf1[4];
#pragma unroll
    for (int m = 0; m < 8; ++m)
      af1[m] = *(const bf16x8*)(pa + (wr * 128 + m * 16 + lr) * 128 + kb1);
#pragma unroll
    for (int n = 0; n < 4; ++n)
      bf1[n] = *(const bf16x8*)(pb + (wc * 64 + n * 16 + lr) * 128 + kb1);
    // all 24 of MY ds_reads materialized in regs before releasing the buffer
    asm volatile("s_waitcnt lgkmcnt(0)" ::: "memory");
    __builtin_amdgcn_sched_barrier(0);
    __builtin_amdgcn_s_barrier();  // every wave done reading buf[kt&1]
    if (kt < 14) {
      const int k0 = (kt + 2) << 6;
      char* da = (char*)sA[kt & 1];
      char* db = (char*)sB[kt & 1];
#pragma unroll
      for (int rr = 0; rr < 4; ++rr) {
        GLOAD(aSrc + (size_t)(rr * 64) * ND + k0, da + rr * 8192 + tid * 16);
        GLOAD(bSrc + (size_t)(rr * 64) * ND + k0, db + rr * 8192 + tid * 16);
      }
    }
    __builtin_amdgcn_s_setprio(1);
#pragma unroll
    for (int m = 0; m < 8; ++m)
#pragma unroll
      for (int n = 0; n < 4; ++n) acc[m][n] = MFMA16(af1[m], bf1[n], acc[m][n]);
    __builtin_amdgcn_s_setprio(0);
  }
  // peeled last k-tile (kt=15, buf 1): only its 8 loads remain in flight
  {
    asm volatile("s_waitcnt vmcnt(0)" ::: "memory");
    __builtin_amdgcn_s_barrier();
    const char* pa = sA[1];
    const char* pb = sB[1];
    bf16x8 af0[8], bf0[4];
#pragma unroll
    for (int m = 0; m < 8; ++m)
      af0[m] = *(const bf16x8*)(pa + (wr * 128 + m * 16 + lr) * 128 + kb0);
#pragma unroll
    for (int n = 0; n < 4; ++n)
      bf0[n] = *(const bf16x8*)(pb + (wc * 64 + n * 16 + lr) * 128 + kb0);
#pragma unroll
    for (int m = 0; m < 8; ++m)
#pragma unroll
      for (int n = 0; n < 4; ++n) acc[m][n] = MFMA16(af0[m], bf0[n], acc[m][n]);
    __builtin_amdgcn_sched_barrier(0);
    bf16x8 af1[8], bf1[4];
#pragma unroll
    for (int m = 0; m < 8; ++m)
      af1[m] = *(const bf16x8*)(pa + (wr * 128 + m * 16 + lr) * 128 + kb1);
#pragma unroll
    for (int n = 0; n < 4; ++n)
      bf1[n] = *(const bf16x8*)(pb + (wc * 64 + n * 16 + lr) * 128 + kb1);
    asm volatile("s_waitcnt lgkmcnt(0)" ::: "memory");
    __builtin_amdgcn_sched_barrier(0);
    __builtin_amdgcn_s_barrier();  // LDS free for the epilogue
#pragma unroll
    for (int m = 0; m < 8; ++m)
#pragma unroll
      for (int n = 0; n < 4; ++n) acc[m][n] = MFMA16(af1[m], bf1[n], acc[m][n]);
  }

  // fused top-2 per row over this block's 256 columns
  float4* red = (float4*)sA;  // [256 rows][4 wave-cols]
#pragma unroll
  for (int m = 0; m < 8; ++m) {
#pragma unroll
    for (int q = 0; q < 4; ++q) {
      float v1 = acc[m][0][q];
      int k1 = bn * 256 + wc * 64 + lr;
      float v2 = -INFINITY;
      int k2 = 0x7fffffff;
#pragma unroll
      for (int n = 1; n < 4; ++n) {
        top2_merge(v1, k1, v2, k2, acc[m][n][q],
                   bn * 256 + wc * 64 + n * 16 + lr, -INFINITY, 0x7fffffff);
      }
#pragma unroll
      for (int msk = 1; msk < 16; msk <<= 1) {
        float ov1 = __shfl_xor(v1, msk);
        int ok1 = __shfl_xor(k1, msk);
        float ov2 = __shfl_xor(v2, msk);
        int ok2 = __shfl_xor(k2, msk);
        top2_merge(v1, k1, v2, k2, ov1, ok1, ov2, ok2);
      }
      if (lr == 0) {
        int row = wr * 128 + m * 16 + lk * 4 + q;
        red[row * 4 + wc] =
            make_float4(v1, __int_as_float(k1), v2, __int_as_float(k2));
      }
    }
  }
  __syncthreads();
  if (tid < 256) {
    float4 e0 = red[tid * 4 + 0];
    float v1 = e0.x; int k1 = __float_as_int(e0.y);
    float v2 = e0.z; int k2 = __float_as_int(e0.w);
#pragma unroll
    for (int j = 1; j < 4; ++j) {
      float4 e = red[tid * 4 + j];
      top2_merge(v1, k1, v2, k2, e.x, __float_as_int(e.y), e.z,
                 __float_as_int(e.w));
    }
    part[(size_t)(bm * 256 + tid) * 16 + bn] =
        make_float4(v1, __int_as_float(k1), v2, __int_as_float(k2));
  }
}

// Merge partials, exact fp32 rescore of margin candidates, update residual
// (f32, in d_out), refresh Ah, active, emit index.
__global__ __launch_bounds__(256) void k_update(
    float* __restrict__ resid, const float* __restrict__ cb,
    const float4* __restrict__ part, int* __restrict__ active,
    float* __restrict__ out_idx, unsigned short* __restrict__ Ah, float decay,
    int s) {
  int b = blockIdx.x, t = threadIdx.x;
  __shared__ int s_cnt;
  __shared__ int s_k[16];
  __shared__ float s_red[4];
  __shared__ float s_bv;
  __shared__ int s_bk;

  float4 r = ((const float4*)(resid + (size_t)b * ND))[t];

  if (t < 32) {
    float4 e = part[(size_t)b * 16 + (t >> 1)];
    float v = (t & 1) ? e.z : e.x;
    int k = __float_as_int((t & 1) ? e.w : e.y);
    float M = v;
#pragma unroll
    for (int off = 16; off > 0; off >>= 1) M = fmaxf(M, __shfl_xor(M, off));
    bool cand = (v >= M - MARGIN);
    unsigned long long mask = __ballot(cand);
    int slot = __popcll(mask & ((1ull << t) - 1ull));
    if (cand && slot < 16) s_k[slot] = k;
    if (t == 0) {
      int n = (int)__popcll(mask);
      s_cnt = n < 16 ? n : 16;
      s_bv = -INFINITY;
      s_bk = 0x7fffffff;
    }
  }
  __syncthreads();
  int cnt = s_cnt;
  for (int c = 0; c < cnt; ++c) {
    int k = s_k[c];
    float4 cv = ((const float4*)(cb + (size_t)k * ND))[t];
    float d = r.x * cv.x + r.y * cv.y + r.z * cv.z + r.w * cv.w;
    d = wave_reduce_sum(d);
    if ((t & 63) == 0) s_red[t >> 6] = d;
    __syncthreads();
    if (t == 0) {
      float sc = s_red[0] + s_red[1] + s_red[2] + s_red[3];
      if (sc > s_bv || (sc == s_bv && k < s_bk)) { s_bv = sc; s_bk = k; }
    }
    __syncthreads();
  }
  int kbest = s_bk;
  int act = active[b];
  float4 cv = ((const float4*)(cb + (size_t)kbest * ND))[t];
  if (act) {
    r.x -= decay * cv.x;
    r.y -= decay * cv.y;
    r.z -= decay * cv.z;
    r.w -= decay * cv.w;
  }
  ((float4*)(resid + (size_t)b * ND))[t] = r;
  ushort4 h;
  h.x = f2bf(r.x); h.y = f2bf(r.y); h.z = f2bf(r.z); h.w = f2bf(r.w);
  ((ushort4*)(Ah + (size_t)b * ND))[t] = h;
  float ss = r.x * r.x + r.y * r.y + r.z * r.z + r.w * r.w;
  ss = wave_reduce_sum(ss);
  if ((t & 63) == 0) s_red[t >> 6] = ss;
  __syncthreads();
  if (t == 0) {
    float tot = s_red[0] + s_red[1] + s_red[2] + s_red[3];
    out_idx[(size_t)b * NL + s] = act ? (float)kbest : -1.0f;
    active[b] = (act && sqrtf(tot) >= RES_THR) ? 1 : 0;
  }
}

extern "C" void kernel_launch(void* const* d_in, const int* in_sizes, int n_in,
                              void* d_out, int out_size, void* d_ws,
                              size_t ws_size, hipStream_t stream) {
  const float* targets = (const float*)d_in[0];
  const float* codebook = (const float*)d_in[1];
  float* out = (float*)d_out;
  float* out_idx = out;                   // [8192][8] indices as f32
  float* resid = out + (size_t)NB * NL;   // [8192][1024] f32 residual

  char* ws = (char*)d_ws;
  float4* part = (float4*)ws;                                    // 2MB
  int* active = (int*)(ws + (size_t)4 * 1024 * 1024);            // 64KB pad
  unsigned short* Ah =
      (unsigned short*)(ws + (size_t)4 * 1024 * 1024 + 65536);   // 16MB
  unsigned short* Bh = Ah + (size_t)NB * ND;                     // 8MB

  k_prep<<<NK, 256, 0, stream>>>(codebook, Bh);
  k_init<<<NB, 256, 0, stream>>>(targets, resid, Ah, active);
  for (int s = 0; s < NL; ++s) {
    k_score<<<(NB / 256) * (NK / 256), 512, 0, stream>>>(Ah, Bh, part);
    float decay = (float)pow(0.9, (double)s);
    k_update<<<NB, 256, 0, stream>>>(resid, codebook, part, active, out_idx, Ah,
                                     decay, s);
  }
}